// Round 14
// baseline (64.441 us; speedup 1.0000x reference)
//
#include <hip/hip_runtime.h>
#include <hip/hip_bf16.h>
#include <math.h>

// vec[b,e] = sum_s softmax_s( tanh(theta@w.T [b,:] + h[b,s,:]@u) @ v ) * h[b,s,e]
// B=64, S=2048, E=256, T=100
// R14 = R13 + per-wave u-slice hoisted into registers ONCE per block
//       (ub[8][4] = 128 VGPR, amortized over NC=8 chunks). Staging stays
//       register-free (global_load_lds, pre-swizzled source), so the total
//       register budget fits in (256,2) without spill. K-loop is now pure
//       LDS + cvt + MFMA -> chunk time collapses to the 32KB stage time.

#define E_DIM 256
#define GM 32        // s-rows per chunk
#define NC 8         // chunks per block

typedef __bf16 bf16x8 __attribute__((ext_vector_type(8)));
typedef float  f32x4  __attribute__((ext_vector_type(4)));

__device__ __forceinline__ unsigned short f2bf(float x) {
    return __builtin_bit_cast(unsigned short, (__bf16)x);
}

// tanh(x) = 1 - 2/(exp(2x)+1); overflow-safe (rcp(inf)=0).
__device__ __forceinline__ float fast_tanh(float x) {
    const float e = __expf(2.0f * x);
    const float r = __builtin_amdgcn_rcpf(e + 1.0f);
    return fmaf(-2.0f, r, 1.0f);
}

// slot swizzle within a 64-slot (16B each) fp32 row: XOR low 4 slot bits
// with row&15. Involution; identical on stage-source and read side.
__device__ __forceinline__ unsigned sswz(unsigned slot, unsigned row) {
    return (slot & 48u) | ((slot & 15u) ^ (row & 15u));
}

// ---------------- Kernel 0 (fused prep): u transpose + theta@w.T ----------------
__global__ __launch_bounds__(256) void k_prep(const float* __restrict__ u,
                                              const float* __restrict__ theta,
                                              const float* __restrict__ w,
                                              unsigned short* __restrict__ u_t,
                                              float* __restrict__ tw,
                                              int T) {
    if (blockIdx.x < E_DIM) {
        const int f = blockIdx.x, e = threadIdx.x;
        u_t[(size_t)f * E_DIM + e] = f2bf(u[(size_t)e * E_DIM + f]);
    } else {
        __shared__ float th[128];
        const int b = blockIdx.x - E_DIM;
        const int e = threadIdx.x;
        if (threadIdx.x < T) th[threadIdx.x] = theta[b * T + threadIdx.x];
        __syncthreads();
        float acc = 0.f;
        for (int t = 0; t < T; ++t) acc = fmaf(th[t], w[e * T + t], acc);
        tw[b * E_DIM + e] = acc;
    }
}

// ---------------- Kernel 1 (fused gate + chunk softmax + weighted partial) ----
__global__ __launch_bounds__(256, 2) void k_fused(const float* __restrict__ h,
                                                  const unsigned short* __restrict__ u_t,
                                                  const float* __restrict__ tw_,
                                                  const float* __restrict__ v,
                                                  float* __restrict__ partial,
                                                  float* __restrict__ pm,
                                                  float* __restrict__ pd,
                                                  int S, int SC) {
    __shared__ float Abuf[2][GM * E_DIM];   // 2 x 32 KB fp32, slot-swizzled
    __shared__ float red[4][GM];            // 512 B
    __shared__ float exw[GM];               // 128 B
    __shared__ float pacc[4][E_DIM];        // 4 KB

    const int b   = blockIdx.y;
    const int c0  = blockIdx.x * NC;        // first chunk (of SC) for this block
    const int tid = threadIdx.x;
    const int w   = tid >> 6;               // wave 0..3
    const int l   = tid & 63;
    const int lg  = l >> 4;                 // 0..3
    const int lc  = l & 15;                 // 0..15
    const int f0w = w * 64;                 // wave's f-range base

    // stage chunk ch into Abuf[buf]: 8 rounds; wave w stages row r*4+w (1 KB)
    // per round; LDS dest linear (lane i at base + 16i); source pre-swizzled.
#define STAGE(buf, ch)                                                           \
    {                                                                            \
        const char* hb_ = (const char*)(h + ((size_t)b * S + (size_t)(ch) * GM) * E_DIM); \
        _Pragma("unroll")                                                        \
        for (int r = 0; r < 8; ++r) {                                            \
            const int row = r * 4 + w;                                           \
            const unsigned ss = sswz((unsigned)l, (unsigned)row);                \
            __builtin_amdgcn_global_load_lds(                                    \
                (const __attribute__((address_space(1))) void*)(hb_ + (size_t)row * 1024 + ss * 16), \
                (__attribute__((address_space(3))) void*)((char*)Abuf[buf] + r * 4096 + w * 1024), \
                16, 0, 0);                                                       \
        }                                                                        \
    }

    // ---- issue stage of chunk 0 first (HBM), then hoisted u preload (L2) ----
    STAGE(0, c0);

    // per-wave u-slice in registers, loaded ONCE (128 VGPR, amortized 8x)
    bf16x8 ub[8][4];   // [kt][n]
#pragma unroll
    for (int kt = 0; kt < 8; ++kt)
#pragma unroll
        for (int n = 0; n < 4; ++n)
            ub[kt][n] = *reinterpret_cast<const bf16x8*>(
                u_t + (size_t)(f0w + n * 16 + lc) * E_DIM + kt * 32 + lg * 8);

    // per-wave epilogue constants
    float tw_f[4], v_f[4];
#pragma unroll
    for (int n = 0; n < 4; ++n) {
        const int f = f0w + n * 16 + lc;
        tw_f[n] = tw_[b * E_DIM + f];
        v_f[n]  = v[f];
    }

    __syncthreads();   // implicit vmcnt(0): tile 0 (and ub) ready

    for (int c = 0; c < NC; ++c) {
        const int sc  = c0 + c;
        const int cur = c & 1;

        // ---- issue-early: stage chunk c+1 into the other buffer ----
        if (c + 1 < NC) STAGE(cur ^ 1, sc + 1);

        // ---- K loop on Abuf[cur]: 8 k-steps of 32; pure LDS + cvt + MFMA ----
        const char* A = (const char*)Abuf[cur];
        f32x4 acc[2][4];
#pragma unroll
        for (int m = 0; m < 2; ++m)
#pragma unroll
            for (int n = 0; n < 4; ++n)
                acc[m][n] = (f32x4){0.f, 0.f, 0.f, 0.f};

#pragma unroll
        for (int kt = 0; kt < 8; ++kt) {
            bf16x8 af[2];
#pragma unroll
            for (int m = 0; m < 2; ++m) {
                const unsigned row = (unsigned)(m * 16 + lc);
                const unsigned s0 = sswz((unsigned)(kt * 8 + lg * 2), row);
                const unsigned s1 = sswz((unsigned)(kt * 8 + lg * 2 + 1), row);
                const f32x4 fa0 = *reinterpret_cast<const f32x4*>(A + row * 1024 + s0 * 16);
                const f32x4 fa1 = *reinterpret_cast<const f32x4*>(A + row * 1024 + s1 * 16);
#pragma unroll
                for (int j = 0; j < 4; ++j) {
                    af[m][j]     = (__bf16)fa0[j];
                    af[m][4 + j] = (__bf16)fa1[j];
                }
            }
#pragma unroll
            for (int n = 0; n < 4; ++n) {
                acc[0][n] = __builtin_amdgcn_mfma_f32_16x16x32_bf16(af[0], ub[kt][n], acc[0][n], 0, 0, 0);
                acc[1][n] = __builtin_amdgcn_mfma_f32_16x16x32_bf16(af[1], ub[kt][n], acc[1][n], 0, 0, 0);
            }
        }

        // ---- gate epilogue: tanh(z+tw)*v, reduce over f ----
        float rs[2][4] = {};   // [m][i]; row = m*16 + lg*4 + i
#pragma unroll
        for (int n = 0; n < 4; ++n)
#pragma unroll
            for (int m = 0; m < 2; ++m)
#pragma unroll
                for (int i = 0; i < 4; ++i)
                    rs[m][i] += fast_tanh(acc[m][n][i] + tw_f[n]) * v_f[n];

#pragma unroll
        for (int off = 1; off < 16; off <<= 1)
#pragma unroll
            for (int m = 0; m < 2; ++m)
#pragma unroll
                for (int i = 0; i < 4; ++i)
                    rs[m][i] += __shfl_xor(rs[m][i], off, 64);

        if (lc == 0) {
#pragma unroll
            for (int m = 0; m < 2; ++m)
#pragma unroll
                for (int i = 0; i < 4; ++i)
                    red[w][m * 16 + lg * 4 + i] = rs[m][i];
        }
        __syncthreads();   // B1: red ready (stage c+1 had the whole K-loop to land)

        // ---- chunk softmax stats: lanes 0..31 own the 32 g values ----
        if (tid < GM) {
            const float g = red[0][tid] + red[1][tid] + red[2][tid] + red[3][tid];
            float mx = g;
#pragma unroll
            for (int off = 1; off < 32; off <<= 1)
                mx = fmaxf(mx, __shfl_xor(mx, off, 64));
            const float ex = __expf(g - mx);
            float d = ex;
#pragma unroll
            for (int off = 1; off < 32; off <<= 1)
                d += __shfl_xor(d, off, 64);
            exw[tid] = ex;
            if (tid == 0) {
                pm[(size_t)b * SC + sc] = mx;
                pd[(size_t)b * SC + sc] = d;
            }
        }
        __syncthreads();   // B2: exw ready

        // ---- weighted partial (fp32): wave w sums rows w*8..w*8+7 ----
        // Lane l reads LDS slot sswz(l,row), which CONTAINS global slot l
        // (involution), so lane l always accumulates e-cols l*4..l*4+3.
        f32x4 a4 = (f32x4){0.f, 0.f, 0.f, 0.f};
#pragma unroll
        for (int j = 0; j < 8; ++j) {
            const unsigned row = (unsigned)(w * 8 + j);
            const float ws = exw[row];
            const unsigned ss = sswz((unsigned)l, row);
            const f32x4 hv = *reinterpret_cast<const f32x4*>(A + row * 1024 + ss * 16);
            a4[0] = fmaf(ws, hv[0], a4[0]);
            a4[1] = fmaf(ws, hv[1], a4[1]);
            a4[2] = fmaf(ws, hv[2], a4[2]);
            a4[3] = fmaf(ws, hv[3], a4[3]);
        }
        *reinterpret_cast<f32x4*>(&pacc[w][l * 4]) = a4;
        __syncthreads();   // B3: pacc ready; all reads of Abuf[cur] done

        partial[((size_t)b * SC + sc) * E_DIM + tid] =
            pacc[0][tid] + pacc[1][tid] + pacc[2][tid] + pacc[3][tid];
    }
#undef STAGE
}

// ---------------- Kernel 2: exact softmax merge across chunks ----------------
__global__ __launch_bounds__(256) void k_combine(const float* __restrict__ partial,
                                                 const float* __restrict__ pm,
                                                 const float* __restrict__ pd,
                                                 float* __restrict__ out,
                                                 int SC) {
    const int b = blockIdx.x, t = threadIdx.x;
    __shared__ float sm[128], sd[128];
    if (t < SC) {
        sm[t] = pm[(size_t)b * SC + t];
        sd[t] = pd[(size_t)b * SC + t];
    }
    __syncthreads();

    float M = -3.4e38f;
    for (int c = 0; c < SC; ++c) M = fmaxf(M, sm[c]);

    float num = 0.f, den = 0.f;
    for (int c = 0; c < SC; ++c) {
        const float s = __expf(sm[c] - M);
        den = fmaf(s, sd[c], den);
        num = fmaf(s, partial[((size_t)b * SC + c) * E_DIM + t], num);
    }
    out[(size_t)b * E_DIM + t] = num / den;
}

extern "C" void kernel_launch(void* const* d_in, const int* in_sizes, int n_in,
                              void* d_out, int out_size, void* d_ws, size_t ws_size,
                              hipStream_t stream) {
    const float* h     = (const float*)d_in[0];
    const float* theta = (const float*)d_in[1];
    const float* w     = (const float*)d_in[2];
    const float* v     = (const float*)d_in[3];
    const float* u     = (const float*)d_in[4];
    float* out = (float*)d_out;

    const int E = in_sizes[3];              // 256
    const int T = in_sizes[2] / E;          // 100
    const int B = in_sizes[1] / T;          // 64
    const int S = in_sizes[0] / (B * E);    // 2048
    const int SC = S / GM;                  // 64

    float* tw = (float*)d_ws;                                     // [B,E]
    unsigned short* u_t = (unsigned short*)(tw + (size_t)B * E);  // [E,E] bf16
    float* partial = (float*)(u_t + (size_t)E * E);               // [B,SC,E]
    float* pm = partial + (size_t)B * SC * E;                     // [B,SC]
    float* pd = pm + (size_t)B * SC;                              // [B,SC]

    k_prep<<<dim3(E + B), dim3(256), 0, stream>>>(u, theta, w, u_t, tw, T);
    k_fused<<<dim3(SC / NC, B), dim3(256), 0, stream>>>(h, u_t, tw, v, partial, pm, pd, S, SC);
    k_combine<<<dim3(B), dim3(256), 0, stream>>>(partial, pm, pd, out, SC);
}

// Round 15
// 59.772 us; speedup vs baseline: 1.0781x; 1.0781x over previous
//
#include <hip/hip_runtime.h>
#include <hip/hip_bf16.h>
#include <math.h>

// vec[b,e] = sum_s softmax_s( tanh(theta@w.T [b,:] + h[b,s,:]@u) @ v ) * h[b,s,e]
// B=64, S=2048, E=256, T=100
// R15 = R14 + T4 counted-vmcnt pipeline:
//   - raw s_barrier + "s_waitcnt vmcnt(8)" at loop top: waits ONLY for the
//     previous chunk's stage; the freshly issued 8 global_load_lds for c+1
//     stay in flight across all barriers (no more vmcnt(0) drain per chunk).
//   - in-loop VMEM = exactly the 8 stage loads/wave (u register-hoisted,
//     stores moved out of the loop) so the vmcnt count is exact.
//   - no-max softmax (|g| <= sum|v| ~ 10.3, exp overflow-safe): per-chunk
//     softmax phase collapses into the weighted-sum phase.
//   - num/den accumulated in REGISTERS across all NC chunks; single write
//     per block at the end. 3 raw barriers per chunk.

#define E_DIM 256
#define GM 32        // s-rows per chunk
#define NC 8         // chunks per block

typedef __bf16 bf16x8 __attribute__((ext_vector_type(8)));
typedef float  f32x4  __attribute__((ext_vector_type(4)));

__device__ __forceinline__ unsigned short f2bf(float x) {
    return __builtin_bit_cast(unsigned short, (__bf16)x);
}

// tanh(x) = 1 - 2/(exp(2x)+1); overflow-safe (rcp(inf)=0).
__device__ __forceinline__ float fast_tanh(float x) {
    const float e = __expf(2.0f * x);
    const float r = __builtin_amdgcn_rcpf(e + 1.0f);
    return fmaf(-2.0f, r, 1.0f);
}

// slot swizzle within a 64-slot (16B each) fp32 row: XOR low 4 slot bits
// with row&15. Involution; identical on stage-source and read side.
__device__ __forceinline__ unsigned sswz(unsigned slot, unsigned row) {
    return (slot & 48u) | ((slot & 15u) ^ (row & 15u));
}

// ---------------- Kernel 0 (fused prep): u transpose + theta@w.T ----------------
__global__ __launch_bounds__(256) void k_prep(const float* __restrict__ u,
                                              const float* __restrict__ theta,
                                              const float* __restrict__ w,
                                              unsigned short* __restrict__ u_t,
                                              float* __restrict__ tw,
                                              int T) {
    if (blockIdx.x < E_DIM) {
        const int f = blockIdx.x, e = threadIdx.x;
        u_t[(size_t)f * E_DIM + e] = f2bf(u[(size_t)e * E_DIM + f]);
    } else {
        __shared__ float th[128];
        const int b = blockIdx.x - E_DIM;
        const int e = threadIdx.x;
        if (threadIdx.x < T) th[threadIdx.x] = theta[b * T + threadIdx.x];
        __syncthreads();
        float acc = 0.f;
        for (int t = 0; t < T; ++t) acc = fmaf(th[t], w[e * T + t], acc);
        tw[b * E_DIM + e] = acc;
    }
}

// ---------------- Kernel 1 (fused, counted-vmcnt pipelined) ----------------
__global__ __launch_bounds__(256, 2) void k_fused(const float* __restrict__ h,
                                                  const unsigned short* __restrict__ u_t,
                                                  const float* __restrict__ tw_,
                                                  const float* __restrict__ v,
                                                  float* __restrict__ partial,
                                                  float* __restrict__ pd,
                                                  int S, int SC) {
    __shared__ float Abuf[2][GM * E_DIM];   // 2 x 32 KB fp32, slot-swizzled
    __shared__ float red[4][GM];            // 512 B
    __shared__ float pacc[4][E_DIM];        // 4 KB
    __shared__ float dred[4];

    const int b   = blockIdx.y;
    const int c0  = blockIdx.x * NC;        // first chunk for this block
    const int tid = threadIdx.x;
    const int w   = tid >> 6;               // wave 0..3
    const int l   = tid & 63;
    const int lg  = l >> 4;                 // 0..3
    const int lc  = l & 15;                 // 0..15
    const int f0w = w * 64;                 // wave's f-range base

    // stage chunk ch into Abuf[buf]: 8 global_load_lds per WAVE (exact vmcnt
    // count). LDS dest linear (lane i at base + 16i); source pre-swizzled.
#define STAGE(buf, ch)                                                           \
    {                                                                            \
        const char* hb_ = (const char*)(h + ((size_t)b * S + (size_t)(ch) * GM) * E_DIM); \
        _Pragma("unroll")                                                        \
        for (int r = 0; r < 8; ++r) {                                            \
            const int row = r * 4 + w;                                           \
            const unsigned ss = sswz((unsigned)l, (unsigned)row);                \
            __builtin_amdgcn_global_load_lds(                                    \
                (const __attribute__((address_space(1))) void*)(hb_ + (size_t)row * 1024 + ss * 16), \
                (__attribute__((address_space(3))) void*)((char*)Abuf[buf] + r * 4096 + w * 1024), \
                16, 0, 0);                                                       \
        }                                                                        \
    }

    // ---- prologue: stage chunk 0 (HBM), hoist u-slice (L2, 128 VGPR), consts ----
    STAGE(0, c0);

    bf16x8 ub[8][4];   // [kt][n]
#pragma unroll
    for (int kt = 0; kt < 8; ++kt)
#pragma unroll
        for (int n = 0; n < 4; ++n)
            ub[kt][n] = *reinterpret_cast<const bf16x8*>(
                u_t + (size_t)(f0w + n * 16 + lc) * E_DIM + kt * 32 + lg * 8);

    float tw_f[4], v_f[4];
#pragma unroll
    for (int n = 0; n < 4; ++n) {
        const int f = f0w + n * 16 + lc;
        tw_f[n] = tw_[b * E_DIM + f];
        v_f[n]  = v[f];
    }

    f32x4 numa = (f32x4){0.f, 0.f, 0.f, 0.f};   // running weighted sum, e=l*4..+3
    float den = 0.f;                             // running denominator (wave rows)

    for (int c = 0; c < NC; ++c) {
        const int cur = c & 1;

        // ---- issue stage c+1; wait ONLY for stage c (counted vmcnt) ----
        if (c + 1 < NC) {
            STAGE(cur ^ 1, c0 + c + 1);
            asm volatile("s_waitcnt vmcnt(8)" ::: "memory");
        } else {
            asm volatile("s_waitcnt vmcnt(0)" ::: "memory");
        }
        __builtin_amdgcn_s_barrier();
        __builtin_amdgcn_sched_barrier(0);

        // ---- K loop on Abuf[cur]: pure LDS + cvt + MFMA ----
        const char* A = (const char*)Abuf[cur];
        f32x4 acc[2][4];
#pragma unroll
        for (int m = 0; m < 2; ++m)
#pragma unroll
            for (int n = 0; n < 4; ++n)
                acc[m][n] = (f32x4){0.f, 0.f, 0.f, 0.f};

#pragma unroll
        for (int kt = 0; kt < 8; ++kt) {
            bf16x8 af[2];
#pragma unroll
            for (int m = 0; m < 2; ++m) {
                const unsigned row = (unsigned)(m * 16 + lc);
                const unsigned s0 = sswz((unsigned)(kt * 8 + lg * 2), row);
                const unsigned s1 = sswz((unsigned)(kt * 8 + lg * 2 + 1), row);
                const f32x4 fa0 = *reinterpret_cast<const f32x4*>(A + row * 1024 + s0 * 16);
                const f32x4 fa1 = *reinterpret_cast<const f32x4*>(A + row * 1024 + s1 * 16);
#pragma unroll
                for (int j = 0; j < 4; ++j) {
                    af[m][j]     = (__bf16)fa0[j];
                    af[m][4 + j] = (__bf16)fa1[j];
                }
            }
#pragma unroll
            for (int n = 0; n < 4; ++n) {
                acc[0][n] = __builtin_amdgcn_mfma_f32_16x16x32_bf16(af[0], ub[kt][n], acc[0][n], 0, 0, 0);
                acc[1][n] = __builtin_amdgcn_mfma_f32_16x16x32_bf16(af[1], ub[kt][n], acc[1][n], 0, 0, 0);
            }
        }

        // ---- gate epilogue: tanh(z+tw)*v, reduce over f (lc classes) ----
        float rs[2][4] = {};   // [m][i]; row = m*16 + lg*4 + i
#pragma unroll
        for (int n = 0; n < 4; ++n)
#pragma unroll
            for (int m = 0; m < 2; ++m)
#pragma unroll
                for (int i = 0; i < 4; ++i)
                    rs[m][i] += fast_tanh(acc[m][n][i] + tw_f[n]) * v_f[n];

#pragma unroll
        for (int off = 1; off < 16; off <<= 1)
#pragma unroll
            for (int m = 0; m < 2; ++m)
#pragma unroll
                for (int i = 0; i < 4; ++i)
                    rs[m][i] += __shfl_xor(rs[m][i], off, 64);

        if (lc == 0) {
#pragma unroll
            for (int m = 0; m < 2; ++m)
#pragma unroll
                for (int i = 0; i < 4; ++i)
                    red[w][m * 16 + lg * 4 + i] = rs[m][i];
        }
        asm volatile("s_waitcnt lgkmcnt(0)" ::: "memory");
        __builtin_amdgcn_s_barrier();
        __builtin_amdgcn_sched_barrier(0);

        // ---- fused softmax(no-max) + weighted accumulate, all waves ----
        // wave w owns rows w*8..w*8+7; every lane recomputes ex (broadcast reads)
#pragma unroll
        for (int j = 0; j < 8; ++j) {
            const unsigned row = (unsigned)(w * 8 + j);
            const float g = red[0][row] + red[1][row] + red[2][row] + red[3][row];
            const float ex = __expf(g);          // |g| <= sum|v_f| ~ 10.3: safe
            den += ex;
            const unsigned ss = sswz((unsigned)l, row);
            const f32x4 hv = *reinterpret_cast<const f32x4*>(A + row * 1024 + ss * 16);
            numa[0] = fmaf(ex, hv[0], numa[0]);
            numa[1] = fmaf(ex, hv[1], numa[1]);
            numa[2] = fmaf(ex, hv[2], numa[2]);
            numa[3] = fmaf(ex, hv[3], numa[3]);
        }
        asm volatile("s_waitcnt lgkmcnt(0)" ::: "memory");
        __builtin_amdgcn_s_barrier();           // buf[cur] reads done -> next STAGE may overwrite
        __builtin_amdgcn_sched_barrier(0);
    }

    // ---- block epilogue: one write of num/den ----
    *reinterpret_cast<f32x4*>(&pacc[w][l * 4]) = numa;
    if (l == 0) dred[w] = den;
    __syncthreads();

    const int nb = SC / NC;                 // blocks per b (8)
    partial[((size_t)b * nb + blockIdx.x) * E_DIM + tid] =
        pacc[0][tid] + pacc[1][tid] + pacc[2][tid] + pacc[3][tid];
    if (tid == 0)
        pd[(size_t)b * nb + blockIdx.x] = dred[0] + dred[1] + dred[2] + dred[3];
#undef STAGE
}

// ---------------- Kernel 2: merge across blocks (no-max softmax: plain sums) ----
__global__ __launch_bounds__(256) void k_combine(const float* __restrict__ partial,
                                                 const float* __restrict__ pd,
                                                 float* __restrict__ out,
                                                 int NB) {
    const int b = blockIdx.x, t = threadIdx.x;
    float den = 0.f;
    for (int k = 0; k < NB; ++k) den += pd[(size_t)b * NB + k];
    float num = 0.f;
    for (int k = 0; k < NB; ++k)
        num += partial[((size_t)b * NB + k) * E_DIM + t];
    out[(size_t)b * E_DIM + t] = num / den;
}

extern "C" void kernel_launch(void* const* d_in, const int* in_sizes, int n_in,
                              void* d_out, int out_size, void* d_ws, size_t ws_size,
                              hipStream_t stream) {
    const float* h     = (const float*)d_in[0];
    const float* theta = (const float*)d_in[1];
    const float* w     = (const float*)d_in[2];
    const float* v     = (const float*)d_in[3];
    const float* u     = (const float*)d_in[4];
    float* out = (float*)d_out;

    const int E = in_sizes[3];              // 256
    const int T = in_sizes[2] / E;          // 100
    const int B = in_sizes[1] / T;          // 64
    const int S = in_sizes[0] / (B * E);    // 2048
    const int SC = S / GM;                  // 64
    const int NB = SC / NC;                 // 8 blocks per b

    float* tw = (float*)d_ws;                                     // [B,E]
    unsigned short* u_t = (unsigned short*)(tw + (size_t)B * E);  // [E,E] bf16
    float* partial = (float*)(u_t + (size_t)E * E);               // [B,NB,E]
    float* pd = partial + (size_t)B * NB * E;                     // [B,NB]

    k_prep<<<dim3(E + B), dim3(256), 0, stream>>>(u, theta, w, u_t, tw, T);
    k_fused<<<dim3(NB, B), dim3(256), 0, stream>>>(h, u_t, tw, v, partial, pd, S, SC);
    k_combine<<<dim3(B), dim3(256), 0, stream>>>(partial, pd, out, NB);
}